// Round 13
// baseline (275.704 us; speedup 1.0000x reference)
//
#include <hip/hip_runtime.h>
#include <hip/hip_cooperative_groups.h>
#include <math.h>

namespace cg = cooperative_groups;

#define NN 8192
#define REV_CAP 48
#define KNN_CAP 384   // per-node survivor cap (E[survivors]~72; P(overflow) astronomically small)
#define PF 12         // msg edge-gather prefetch depth
#define LGRID 1536    // cooperative grid: 6 blocks/CU x 256 CU (LDS 26.6KB -> exactly 6/CU)

// ---- ws layout (float element offsets) ----
static const size_t OFF_K     = 0;        // 405
static const size_t OFF_CNT   = 512;      // int[8192]
static const size_t OFF_REV   = 8704;     // int[8192*48]
static const size_t OFF_STATS = 401920;   // 3 layers x (8 slots x (32 pA | 96 pB)) = 3x1024, slot-major
static const size_t OFF_XF    = 406528;   // 8192*120 interleaved features
static const size_t OFF_YF    = 1389568;  // 8192*120 outputs (head aliased as SoA x/y/z/q for KNN)
static const size_t WS_FLOATS = 2372608;

// =================== K tensor math — HOST, once (pure constants) ===================
static double h_dfact(int n){ double r=1.0; for(int i=2;i<=n;++i) r*=(double)i; return r; }

static double h_dcg(int j1,int m1,int j2,int m2,int j3,int m3){
  if (m1+m2!=m3) return 0.0;
  if (j3 < abs(j1-j2) || j3 > j1+j2) return 0.0;
  double pre = sqrt((double)(2*j3+1)*h_dfact(j3+j1-j2)*h_dfact(j3-j1+j2)*h_dfact(j1+j2-j3)/h_dfact(j1+j2+j3+1));
  pre *= sqrt(h_dfact(j3+m3)*h_dfact(j3-m3)*h_dfact(j1-m1)*h_dfact(j1+m1)*h_dfact(j2-m2)*h_dfact(j2+m2));
  double s=0.0;
  for(int k=0;k<=j1+j2-j3;++k){
    int d1=j1+j2-j3-k, d2=j1-m1-k, d3=j2+m2-k, d4=j3-j2+m1+k, d5=j3-j1-m2+k;
    if(d1<0||d2<0||d3<0||d4<0||d5<0) continue;
    double den = h_dfact(k)*h_dfact(d1)*h_dfact(d2)*h_dfact(d3)*h_dfact(d4)*h_dfact(d5);
    s += ((k&1)? -1.0: 1.0)/den;
  }
  return pre*s;
}

static int h_qrow(int l,int r,int* col,double* re,double* im){
  const double s = 0.70710678118654752440;
  if (r==l){ col[0]=l; re[0]=1.0; im[0]=0.0; return 1; }
  if (r>l){ int m=r-l;
    col[0]=l+m; re[0]=((m&1)?-s:s); im[0]=0.0;
    col[1]=l-m; re[1]=s;            im[1]=0.0;
  } else { int m=l-r;
    col[0]=l+m; re[0]=0.0; im[0]=((m&1)? s : -s);
    col[1]=l-m; re[1]=0.0; im[1]=s;
  }
  return 2;
}

static float g_Khost[405];
static bool  g_Kinit = false;
static int   g_coop  = -1;   // -1 unknown, 1 works, 0 failed -> legacy

static void h_computeK(){
  const int sizes[9]={1,25,9,45,75,25,25,75,125};
  const int l1s[9]={0,0,1,1,1,2,2,2,2};
  const int l2s[9]={0,2,0,2,2,0,2,2,2};
  const int l3s[9]={0,2,1,1,2,2,0,1,2};
  for(int tid=0; tid<405; ++tid){
    int p=0, rem=tid;
    for(p=0;p<9;++p){ if(rem < sizes[p]) break; rem -= sizes[p]; }
    const int l1=l1s[p], l2=l2s[p], l3=l3s[p];
    const int n1=2*l1+1, n2=2*l2+1;
    const int c = rem/(n1*n2); const int r2 = rem%(n1*n2); const int a=r2/n2; const int b=r2%n2;

    int c3[2],c1[2],c2[2]; double re3[2],im3[2],re1[2],im1[2],re2[2],im2[2];
    const int nc3 = h_qrow(l3,c,c3,re3,im3);
    const int nc1 = h_qrow(l1,a,c1,re1,im1);
    const int nc2 = h_qrow(l2,b,c2,re2,im2);

    double accRe=0, accIm=0;
    for(int i3=0;i3<nc3;++i3){
      const double q3re=re3[i3], q3im=-im3[i3];
      for(int i1=0;i1<nc1;++i1){
        const double pre_re = q3re*re1[i1] - q3im*im1[i1];
        const double pre_im = q3re*im1[i1] + q3im*re1[i1];
        for(int i2=0;i2<nc2;++i2){
          const double cgv = h_dcg(l1, c1[i1]-l1, l2, c2[i2]-l2, l3, c3[i3]-l3);
          if (cgv==0.0) continue;
          accRe += (pre_re*re2[i2] - pre_im*im2[i2])*cgv;
          accIm += (pre_re*im2[i2] + pre_im*re2[i2])*cgv;
        }
      }
    }
    const bool useImag = ((l1+l2+l3)&1)!=0;
    g_Khost[tid] = (float)(useImag? accIm : accRe);
  }
}

// =================== fused setup: xf init | SoA+q | cnt | stats-zero ===================
__global__ __launch_bounds__(256) void k_setup(const float* __restrict__ pos,
        const float* __restrict__ W_emb,
        float* __restrict__ xf,
        float* __restrict__ xs, float* __restrict__ ys, float* __restrict__ zs,
        float* __restrict__ qs,
        int* __restrict__ cnt, float* __restrict__ stats){
  int idx = blockIdx.x*256 + threadIdx.x;
  if (idx < 983040) { const int c = idx%120; xf[idx] = (c<32)? W_emb[c] : 0.f; return; }
  idx -= 983040;
  if (idx < 8192) {
    const float x=pos[3*idx], y=pos[3*idx+1], z=pos[3*idx+2];
    xs[idx]=x; ys[idx]=y; zs[idx]=z; qs[idx]=0.5f*(x*x+y*y+z*z);
    return;
  }
  idx -= 8192;
  if (idx < 8192) { cnt[idx]=0; return; }
  idx -= 8192;
  if (idx < 3072) stats[idx]=0.f;   // 3 layers x 8 slots x (32 pA | 96 pB)
}

// sortable key: monotonic float->uint map (neg floats < pos floats, order preserved)
__device__ __forceinline__ unsigned fkey(float f){
  const unsigned b = __float_as_uint(f);
  return (b & 0x80000000u) ? ~b : (b | 0x80000000u);
}

// exact 9th-smallest of the 128-element per-wave (m1,m2) multiset via ballot radix-select
__device__ __forceinline__ float rsel9_T(float m1, float m2){
  const unsigned kk1 = fkey(m1), kk2 = fkey(m2);
  unsigned P = 0u; int need = 9;
  #pragma unroll 1
  for(int bit=31; bit>=0; --bit){
    const unsigned pref = P >> bit;
    const int c0 = __popcll(__ballot((kk1>>bit)==pref)) + __popcll(__ballot((kk2>>bit)==pref));
    if (need > c0){ need -= c0; P |= (1u<<bit); }
  }
  return __uint_as_float((P & 0x80000000u) ? (P & 0x7fffffffu) : ~P);
}

// radix-select the exact 9th-smallest (key,id)-lex threshold over KMAX regs/lane,
// then push the selected SET (order irrelevant: 9 distinct targets).
#define RSELECT_PUSH(KMAX) do{ \
  unsigned P = 0u; int need = 9; \
  _Pragma("unroll 1") \
  for(int bit=31; bit>=0; --bit){ \
    const unsigned pref = P >> bit; \
    int c0 = 0; \
    _Pragma("unroll") \
    for(int k=0;k<KMAX;++k) c0 += __popcll(__ballot((ku[k]>>bit)==pref)); \
    if (need > c0){ need -= c0; P |= (1u<<bit); } \
  } \
  int c_eq = 0; \
  _Pragma("unroll") \
  for(int k=0;k<KMAX;++k) c_eq += __popcll(__ballot(ku[k]==P)); \
  bool tsel[KMAX]; \
  _Pragma("unroll") \
  for(int k=0;k<KMAX;++k) tsel[k] = (ku[k]==P); \
  if (c_eq > need){ \
    _Pragma("unroll") \
    for(int k=0;k<KMAX;++k) tsel[k]=false; \
    for(int r=0;r<need;++r){ \
      int mid = 0x7fffffff; \
      _Pragma("unroll") \
      for(int k=0;k<KMAX;++k) if (ku[k]==P && !tsel[k] && il[k]<mid) mid = il[k]; \
      _Pragma("unroll") \
      for(int s=32;s>0;s>>=1){ const int om = __shfl_xor(mid,s,64); mid = (om<mid)? om : mid; } \
      _Pragma("unroll") \
      for(int k=0;k<KMAX;++k) if (ku[k]==P && il[k]==mid) tsel[k]=true; \
    } \
  } \
  _Pragma("unroll") \
  for(int k=0;k<KMAX;++k){ \
    const bool take = (ku[k] < P) || tsel[k]; \
    const int ix = il[k]; \
    if (take && ix != node){ \
      int cpos = atomicAdd(&cnt[ix],1); \
      if (cpos < REV_CAP) rev[ix*REV_CAP + cpos] = node; \
    } \
  } \
}while(0)

// =================== exact 9-NN: 2 nodes/wave, 1-deep prefetch (r11-proven form) ===================
// Variant history: 1-node/wave 48.5us; 2-node/1-deep 44.5us (BEST); 2-node/2-deep 47us
// (hand pipelining beat compiler scheduling, refuted); 4-node r1 and LDS-staging r2/r6 worse.
__global__ __launch_bounds__(256, 8) void k_knn8(const float* __restrict__ xs,
                                              const float* __restrict__ ys,
                                              const float* __restrict__ zs,
                                              const float* __restrict__ qs,
                                              int* __restrict__ cnt, int* __restrict__ rev){
  const int lane = threadIdx.x & 63;
  const int w    = threadIdx.x >> 6;
  const int n0   = blockIdx.x*8 + w*2;      // this wave's nodes: n0, n0+1
  const int w2   = w*2;
  __shared__ float sdist[8][KNN_CAP];
  __shared__ int   sidx[8][KNN_CAP];
  __shared__ int   scount[8];
  if (threadIdx.x < 8) scount[threadIdx.x]=0;
  __syncthreads();

  const float px0 = xs[n0],   py0 = ys[n0],   pz0 = zs[n0];
  const float px1 = xs[n0+1], py1 = ys[n0+1], pz1 = zs[n0+1];

  // Phase 1: per-lane top-2 per node over first 1024 candidates, branchless
  float m1a=INFINITY, m2a=INFINITY, m1b=INFINITY, m2b=INFINITY;
  for(int c=0;c<4;++c){
    const int base = (c*64 + lane)*4;
    const float4 fx = *(const float4*)(xs + base);
    const float4 fy = *(const float4*)(ys + base);
    const float4 fz = *(const float4*)(zs + base);
    const float4 fq = *(const float4*)(qs + base);
    const float cx[4]={fx.x,fx.y,fx.z,fx.w};
    const float cy[4]={fy.x,fy.y,fy.z,fy.w};
    const float cz[4]={fz.x,fz.y,fz.z,fz.w};
    const float cq[4]={fq.x,fq.y,fq.z,fq.w};
    #pragma unroll
    for(int q=0;q<4;++q){
      const float s0 = fmaf(-px0,cx[q], fmaf(-py0,cy[q], fmaf(-pz0,cz[q], cq[q])));
      const float s1 = fmaf(-px1,cx[q], fmaf(-py1,cy[q], fmaf(-pz1,cz[q], cq[q])));
      float hi;
      hi = fmaxf(m1a, s0); m1a = fminf(m1a, s0); m2a = fminf(m2a, hi);
      hi = fmaxf(m1b, s1); m1b = fminf(m1b, s1); m2b = fminf(m2b, hi);
    }
  }
  const float T0 = rsel9_T(m1a, m2a);
  const float T1 = rsel9_T(m1b, m2b);

  // Phase 2: filter all 8192 candidates for both nodes, 1-deep load prefetch
  {
    const int b0 = lane*4;
    float4 nfx = *(const float4*)(xs + b0);
    float4 nfy = *(const float4*)(ys + b0);
    float4 nfz = *(const float4*)(zs + b0);
    float4 nfq = *(const float4*)(qs + b0);
    for(int c=0;c<32;++c){
      const float4 fx=nfx, fy=nfy, fz=nfz, fq=nfq;
      const int cbase = (c*64 + lane)*4;
      if (c<31){
        const int nb2 = ((c+1)*64 + lane)*4;
        nfx = *(const float4*)(xs + nb2);
        nfy = *(const float4*)(ys + nb2);
        nfz = *(const float4*)(zs + nb2);
        nfq = *(const float4*)(qs + nb2);
      }
      const float cx[4]={fx.x,fx.y,fx.z,fx.w};
      const float cy[4]={fy.x,fy.y,fy.z,fy.w};
      const float cz[4]={fz.x,fz.y,fz.z,fz.w};
      const float cq[4]={fq.x,fq.y,fq.z,fq.w};
      #pragma unroll
      for(int q=0;q<4;++q){
        const float s0 = fmaf(-px0,cx[q], fmaf(-py0,cy[q], fmaf(-pz0,cz[q], cq[q])));
        const float s1 = fmaf(-px1,cx[q], fmaf(-py1,cy[q], fmaf(-pz1,cz[q], cq[q])));
        if (s0 <= T0){
          int pos = atomicAdd(&scount[w2],1);
          if (pos < KNN_CAP){ sdist[w2][pos]=s0; sidx[w2][pos]=cbase+q; }
        }
        if (s1 <= T1){
          int pos = atomicAdd(&scount[w2+1],1);
          if (pos < KNN_CAP){ sdist[w2+1][pos]=s1; sidx[w2+1][pos]=cbase+q; }
        }
      }
    }
  }
  __syncthreads();

  // Phase 3: exact top-9 per node, (key,id)-lexicographic, radix-select + set push
  #pragma unroll 1
  for(int u=0;u<2;++u){
    const int node = n0+u;
    const int s_   = w2+u;
    int m = scount[s_]; if (m > KNN_CAP) m = KNN_CAP;
    unsigned ku[KNN_CAP/64]; int il[KNN_CAP/64];
    #pragma unroll
    for(int k=0;k<KNN_CAP/64;++k){
      const int j = lane + 64*k;
      if (j < m){ ku[k]=fkey(sdist[s_][j]); il[k]=sidx[s_][j]; }
      else      { ku[k]=0xffffffffu;        il[k]=0x7fffffff; }
    }
    if (m <= 128) RSELECT_PUSH(2);    // common case (E[m]~72): 2-reg ballots
    else          RSELECT_PUSH(6);    // exact fallback
  }
}

// =================== shared device bodies for msg / norm / mlp (flat-smem versions) ===================
// smem layout (floats), msg phase:  KL 0..405 | TW 405..549 | momPS 549..3429 (4x720)
//   aS 3429..5349 (4x480) | bA 5349..5381 | bB 5381..5477 | eIdx 5477..5669 (int 4x48)
//   eSh 5669..6629 (4x5x48)
// norm phase: sc 0..96 | sf 96..128.  mlp: w1 0..1024 | w2 ..1536 | w3 ..1568 | b2 ..1584
//   b3 ..1586 | sc0 ..1618 | sf0 ..1650 | xvS ..1778 | h1S ..1906 | h2S ..1970

__device__ __forceinline__ void msg_group_body(
  float* __restrict__ smem, int t, int w, int lane, int grp,
  const float* __restrict__ pos, const int* __restrict__ cnt, const int* __restrict__ rev,
  const float* __restrict__ xf,
  const float* __restrict__ W0, const float* __restrict__ W1, const float* __restrict__ W2,
  float* __restrict__ pA, float* __restrict__ pB, float* __restrict__ yf)
{
  float* KL    = smem;
  float* TW    = smem + 405;
  float* momPS = smem + 549;
  float* aS    = smem + 3429;
  float* bA    = smem + 5349;
  float* bB    = smem + 5381;
  int*   eIdx  = (int*)(smem + 5477);
  float* eSh   = smem + 5669;
  const int n = grp*4 + w;

  if (t<96){ bB[t]=0.f; if(t<32) bA[t]=0.f; }

  // Stage 1a: parallel edge geometry
  const int deg0 = cnt[n];
  const int deg = (deg0<REV_CAP)? deg0 : REV_CAP;
  const float pnx=pos[3*n], pny=pos[3*n+1], pnz=pos[3*n+2];
  const float s15 = 3.8729833462f, s5c = 2.2360679775f;
  if (lane < deg){
    const int i = rev[n*REV_CAP+lane];
    eIdx[w*48+lane] = i;
    const float ex = pnx - pos[3*i], ey = pny - pos[3*i+1], ez = pnz - pos[3*i+2];
    const float rn = sqrtf(ex*ex+ey*ey+ez*ez) + 1e-12f;
    const float ux=ex/rn, uy=ey/rn, uz=ez/rn;
    eSh[(w*5+0)*48+lane]=s15*ux*uy;
    eSh[(w*5+1)*48+lane]=s15*uy*uz;
    eSh[(w*5+2)*48+lane]=0.5f*s5c*(3.f*uz*uz-1.f);
    eSh[(w*5+3)*48+lane]=s15*ux*uz;
    eSh[(w*5+4)*48+lane]=0.5f*s15*(ux*ux-uy*uy);
  }
  __syncthreads();

  // Stage 1b: moment accumulation with prefetched gathers
  const int c0 = lane*2;
  float mp0=0.f, mp1=0.f;
  float ms0[5], ms1[5];
  #pragma unroll
  for(int j=0;j<5;++j){ ms0[j]=0.f; ms1[j]=0.f; }

  int idxr[PF];
  #pragma unroll
  for(int k=0;k<PF;++k) idxr[k] = (k<deg)? eIdx[w*48+k] : 0;
  float2 fr[PF];
  if (lane<60){
    #pragma unroll
    for(int k=0;k<PF;++k) fr[k] = *(const float2*)(xf + (size_t)idxr[k]*120 + c0);
  }
  #pragma unroll
  for(int k=0;k<PF;++k){
    if (k<deg){
      const float sh0=eSh[(w*5+0)*48+k], sh1=eSh[(w*5+1)*48+k], sh2=eSh[(w*5+2)*48+k];
      const float sh3=eSh[(w*5+3)*48+k], sh4=eSh[(w*5+4)*48+k];
      if (lane<60){
        const float2 f = fr[k];
        mp0 += f.x; mp1 += f.y;
        ms0[0]+=f.x*sh0; ms0[1]+=f.x*sh1; ms0[2]+=f.x*sh2; ms0[3]+=f.x*sh3; ms0[4]+=f.x*sh4;
        ms1[0]+=f.y*sh0; ms1[1]+=f.y*sh1; ms1[2]+=f.y*sh2; ms1[3]+=f.y*sh3; ms1[4]+=f.y*sh4;
      }
    }
  }
  for(int e=PF;e<deg;++e){   // rare tail (deg>PF)
    const int i = eIdx[w*48+e];
    const float sh0=eSh[(w*5+0)*48+e], sh1=eSh[(w*5+1)*48+e], sh2=eSh[(w*5+2)*48+e];
    const float sh3=eSh[(w*5+3)*48+e], sh4=eSh[(w*5+4)*48+e];
    if (lane<60){
      const float2 f = *(const float2*)(xf + (size_t)i*120 + c0);
      mp0 += f.x; mp1 += f.y;
      ms0[0]+=f.x*sh0; ms0[1]+=f.x*sh1; ms0[2]+=f.x*sh2; ms0[3]+=f.x*sh3; ms0[4]+=f.x*sh4;
      ms1[0]+=f.y*sh0; ms1[1]+=f.y*sh1; ms1[2]+=f.y*sh2; ms1[3]+=f.y*sh3; ms1[4]+=f.y*sh4;
    }
  }
  if (lane<60){
    momPS[w*720+c0]=mp0; momPS[w*720+c0+1]=mp1;
    #pragma unroll
    for(int j=0;j<5;++j){ momPS[w*720+120+c0*5+j]=ms0[j]; momPS[w*720+120+(c0+1)*5+j]=ms1[j]; }
  }
  __syncthreads();

  // Stage 2: balanced K-contraction interpreter — 480 dots/node over 64 lanes.
  #pragma unroll 1
  for(int e=lane; e<480; e+=64){
    int a, b, L, dst; float rw;
    if (e<32){        const int u=e;                            a=0;        b=u;                  L=1;  rw=TW[u];     dst=u; }
    else if (e<192){  const int i=e-32,  u=i/5, o=i%5;          a=1+o*5;    b=120+u*5;            L=5;  rw=TW[32+u];  dst=160+u*5+o; }
    else if (e<240){  const int i=e-192, u=i/3, o=i%3;          a=26+o*3;   b=32+u*3;             L=3;  rw=TW[64+u];  dst=40+u*3+o; }
    else if (e<288){  const int i=e-240, u=i/3, o=i%3;          a=35+o*15;  b=120+(32+u*3)*5;     L=15; rw=TW[80+u];  dst=40+(16+u)*3+o; }
    else if (e<368){  const int i=e-288, u=i/5, o=i%5;          a=80+o*15;  b=120+(32+u*3)*5;     L=15; rw=TW[96+u];  dst=160+(32+u)*5+o; }
    else if (e<408){  const int i=e-368, u=i/5, o=i%5;          a=155+o*5;  b=80+u*5;             L=5;  rw=TW[112+u]; dst=160+(48+u)*5+o; }
    else if (e<416){  const int u=e-408;                        a=180;      b=120+(80+u*5)*5;     L=25; rw=TW[120+u]; dst=32+u; }
    else if (e<440){  const int i=e-416, u=i/3, o=i%3;          a=205+o*25; b=120+(80+u*5)*5;     L=25; rw=TW[128+u]; dst=40+(32+u)*3+o; }
    else {            const int i=e-440, u=i/5, o=i%5;          a=280+o*25; b=120+(80+u*5)*5;     L=25; rw=TW[136+u]; dst=160+(56+u)*5+o; }
    float g=0.f;
    #pragma unroll 1
    for(int k=0;k<L;++k) g += KL[a+k]*momPS[w*720+b+k];
    aS[w*480+dst] = rw*g;
  }
  __syncthreads();

  // Stage 3: linear mixes, write yf[n][120], accumulate block stats partials in LDS
  const float inv40 = 0.15811388300841896660f;
  for(int q=lane;q<120;q+=64){
    float out; int chan;
    if (q<32){
      float g=0.f;
      for(int uu=0;uu<40;++uu) g += aS[w*480+uu]*W0[uu*32+q];
      out = g*inv40; chan = q;
    } else if (q<80){
      const int e=q-32, v=e/3, m=e%3;
      float g=0.f;
      for(int uu=0;uu<40;++uu) g += aS[w*480+40+uu*3+m]*W1[uu*16+v];
      out = g*inv40; chan = 32+v;
    } else {
      const int e=q-80, tt=e/5, m=e%5;
      float g=0.f;
      for(int uu=0;uu<64;++uu) g += aS[w*480+160+uu*5+m]*W2[uu*8+tt];
      out = g*0.125f; chan = 48+tt;
    }
    yf[(size_t)n*120+q] = out;
    atomicAdd(&bB[chan], out*out);
    if (q<32) atomicAdd(&bA[q], out);
  }
  __syncthreads();
  // flush block partials to this XCD's exclusive slot lines (grp&7; LGRID%8==0 keeps it stable)
  if (t<96){
    const int slot = grp & 7;
    atomicAdd(&pB[slot*96 + t], bB[t]);
    if (t<32) atomicAdd(&pA[slot*32 + t], bA[t]);
  }
  __syncthreads();   // protect bA/bB reuse on next group
}

// =================== cooperative layer pipeline: 3x(msg [+norm]) + normmlp, 1 launch ===================
__global__ __launch_bounds__(256, 6) void k_layers(
  const float* __restrict__ pos,
  const int* __restrict__ cnt, const int* __restrict__ rev,
  const float* __restrict__ Kbuf,
  float* __restrict__ xf,
  const float* __restrict__ tp_w,
  const float* __restrict__ lin_W0, const float* __restrict__ lin_W1, const float* __restrict__ lin_W2,
  float* __restrict__ stats,
  float* __restrict__ yf,
  const float* __restrict__ bn_w0, const float* __restrict__ bn_b0,
  const float* __restrict__ bn_w1, const float* __restrict__ bn_w2,
  const float* __restrict__ Wf1, const float* __restrict__ Wf2,
  const float* __restrict__ bf2, const float* __restrict__ Wf3,
  const float* __restrict__ bf3, float* __restrict__ out)
{
  cg::grid_group grid = cg::this_grid();
  __shared__ float smem[6629];
  const int t = threadIdx.x;
  const int w = t>>6, lane = t&63;

  for (int l=0; l<3; ++l){
    const float* tpw = tp_w + l*144;
    const float* W0  = lin_W0 + l*1280;
    const float* W1  = lin_W1 + l*640;
    const float* W2  = lin_W2 + l*512;
    float* pA = stats + l*1024;
    float* pB = pA + 256;

    // ---- MSG phase (grid-stride over 2048 node-groups) ----
    for(int q=t;q<405;q+=256) smem[q]=Kbuf[q];          // KL
    for(int q=t;q<144;q+=256) smem[405+q]=tpw[q];       // TW
    __syncthreads();
    for (int grp = blockIdx.x; grp < NN/4; grp += gridDim.x)
      msg_group_body(smem, t, w, lane, grp, pos, cnt, rev, xf, W0, W1, W2, pA, pB, yf);
    grid.sync();   // all yf + stats(l) complete

    if (l < 2){
      // ---- NORM phase (grid-stride over 3840 chunks) ----
      float* sc = smem; float* sf = smem + 96;
      const float* bw0 = bn_w0 + l*32; const float* bb0 = bn_b0 + l*32;
      const float* bw1 = bn_w1 + l*16; const float* bw2 = bn_w2 + l*8;
      if (t<96){
        float sB=0.f;
        #pragma unroll
        for(int k=0;k<8;++k) sB += pB[k*96+t];
        float scale;
        if (t<32){
          float sA=0.f;
          #pragma unroll
          for(int k=0;k<8;++k) sA += pA[k*32+t];
          const float mean = sA*(1.f/8192.f);
          const float var  = sB*(1.f/8192.f) - mean*mean;
          const float inv  = 1.f/sqrtf(var+1e-5f);
          scale = bw0[t]*inv;
          sf[t] = bb0[t] - mean*scale;
        } else if (t<48){
          scale = bw1[t-32]/sqrtf(sB*(1.f/(8192.f*3.f))+1e-5f);
        } else {
          scale = bw2[t-48]/sqrtf(sB*(1.f/(8192.f*5.f))+1e-5f);
        }
        sc[t]=scale;
      }
      __syncthreads();
      for (int chunk = blockIdx.x; chunk < (NN*120)/256; chunk += gridDim.x){
        const int idx = chunk*256 + t;
        const int c = idx%120;
        const int chan = (c<32)? c : ((c<80)? 32+(c-32)/3 : 48+(c-80)/5);
        const float v = yf[idx]*sc[chan] + ((c<32)? sf[c] : 0.f);
        xf[idx] += fmaxf(v,0.f);
      }
      grid.sync();   // xf(l+1) complete
    }
  }

  // ---- NORMMLP phase (grid-stride over 2048 node-groups; wave-per-node) ----
  {
    float* w1 = smem;          float* w2 = smem+1024;  float* w3 = smem+1536;
    float* b2 = smem+1568;     float* b3 = smem+1584;
    float* sc0 = smem+1586;    float* sf0 = smem+1618;
    float* xvS = smem+1650;    float* h1S = smem+1778; float* h2S = smem+1906;
    const float* pA2 = stats + 2*1024; const float* pB2 = pA2 + 256;
    for(int q=t;q<1024;q+=256) w1[q]=Wf1[q];
    for(int q=t;q<512;q+=256)  w2[q]=Wf2[q];
    if(t<32) w3[t]=Wf3[t];
    if(t<16) b2[t]=bf2[t];
    if(t<2)  b3[t]=bf3[t];
    if(t<32){
      float sA=0.f, sB=0.f;
      #pragma unroll
      for(int k=0;k<8;++k){ sA += pA2[k*32+t]; sB += pB2[k*96+t]; }
      const float mean = sA*(1.f/8192.f);
      const float var  = sB*(1.f/8192.f) - mean*mean;
      const float inv  = 1.f/sqrtf(var+1e-5f);
      sc0[t] = (bn_w0+64)[t]*inv;
      sf0[t] = (bn_b0+64)[t] - mean*sc0[t];
    }
    __syncthreads();
    const float inv32 = 0.17677669529663688110f;
    for (int grp = blockIdx.x; grp < NN/4; grp += gridDim.x){
      const int n = grp*4 + w;
      if (lane<32){
        const float v = yf[(size_t)n*120+lane]*sc0[lane] + sf0[lane];
        xvS[w*32+lane] = xf[(size_t)n*120+lane] + fmaxf(v,0.f);
      }
      __syncthreads();
      if (lane<32){
        float g=0.f;
        #pragma unroll 8
        for(int k=0;k<32;++k) g += xvS[w*32+k]*w1[k*32+lane];
        h1S[w*32+lane] = fmaxf(g*inv32, 0.f);
      }
      __syncthreads();
      if (lane<16){
        float g=b2[lane];
        #pragma unroll 8
        for(int k=0;k<32;++k) g += h1S[w*32+k]*w2[k*16+lane];
        h2S[w*16+lane]=fmaxf(g,0.f);
      }
      __syncthreads();
      if (lane<2){
        float g=b3[lane];
        #pragma unroll
        for(int k=0;k<16;++k) g += h2S[w*16+k]*w3[k*2+lane];
        out[n*2+lane]=g;
      }
      __syncthreads();
    }
  }
}

// =================== legacy fallback kernels (r11-proven) ===================
__global__ __launch_bounds__(256) void k_msg(
  const float* __restrict__ pos,
  const int* __restrict__ cnt, const int* __restrict__ rev,
  const float* __restrict__ Kbuf,
  const float* __restrict__ xf,
  const float* __restrict__ tpw,
  const float* __restrict__ W0, const float* __restrict__ W1, const float* __restrict__ W2,
  float* __restrict__ pA, float* __restrict__ pB,
  float* __restrict__ yf)
{
  __shared__ float smem[6629];
  const int t = threadIdx.x;
  const int w = t>>6, lane = t&63;
  for(int q=t;q<405;q+=256) smem[q]=Kbuf[q];
  for(int q=t;q<144;q+=256) smem[405+q]=tpw[q];
  __syncthreads();
  msg_group_body(smem, t, w, lane, blockIdx.x, pos, cnt, rev, xf, W0, W1, W2, pA, pB, yf);
}

__global__ __launch_bounds__(256) void k_norm(const float* __restrict__ yf,
                       const float* __restrict__ pA, const float* __restrict__ pB,
                       const float* __restrict__ bw0,const float* __restrict__ bb0,
                       const float* __restrict__ bw1,const float* __restrict__ bw2,
                       float* __restrict__ xf){
  __shared__ float sc[96], sf[32];
  const int t = threadIdx.x;
  if (t<96){
    float sB=0.f;
    #pragma unroll
    for(int k=0;k<8;++k) sB += pB[k*96+t];
    float scale;
    if (t<32){
      float sA=0.f;
      #pragma unroll
      for(int k=0;k<8;++k) sA += pA[k*32+t];
      const float mean = sA*(1.f/8192.f);
      const float var  = sB*(1.f/8192.f) - mean*mean;
      const float inv  = 1.f/sqrtf(var+1e-5f);
      scale = bw0[t]*inv;
      sf[t] = bb0[t] - mean*scale;
    } else if (t<48){
      scale = bw1[t-32]/sqrtf(sB*(1.f/(8192.f*3.f))+1e-5f);
    } else {
      scale = bw2[t-48]/sqrtf(sB*(1.f/(8192.f*5.f))+1e-5f);
    }
    sc[t]=scale;
  }
  __syncthreads();
  const int idx = blockIdx.x*256 + t;
  if (idx >= NN*120) return;
  const int c = idx%120;
  const int chan = (c<32)? c : ((c<80)? 32+(c-32)/3 : 48+(c-80)/5);
  const float v = yf[idx]*sc[chan] + ((c<32)? sf[c] : 0.f);
  xf[idx] += fmaxf(v,0.f);
}

__global__ __launch_bounds__(256) void k_normmlp(const float* __restrict__ yf,
                                             const float* __restrict__ xf,
                                             const float* __restrict__ pA, const float* __restrict__ pB,
                                             const float* __restrict__ bw0,const float* __restrict__ bb0,
                                             const float* __restrict__ Wf1,const float* __restrict__ Wf2,
                                             const float* __restrict__ bf2,const float* __restrict__ Wf3,
                                             const float* __restrict__ bf3, float* __restrict__ out){
  __shared__ float w1[1024], w2[512], w3[32], b2[16], b3[2], sc0[32], sf0[32];
  __shared__ float xvS[4][32], h1S[4][32], h2S[4][16];
  const int t=threadIdx.x;
  const int w = t>>6, lane = t&63;
  const int n = blockIdx.x*4 + w;
  for(int q=t;q<1024;q+=256) w1[q]=Wf1[q];
  for(int q=t;q<512;q+=256)  w2[q]=Wf2[q];
  if(t<32) w3[t]=Wf3[t];
  if(t<16) b2[t]=bf2[t];
  if(t<2)  b3[t]=bf3[t];
  if(t<32){
    float sA=0.f, sB=0.f;
    #pragma unroll
    for(int k=0;k<8;++k){ sA += pA[k*32+t]; sB += pB[k*96+t]; }
    const float mean = sA*(1.f/8192.f);
    const float var  = sB*(1.f/8192.f) - mean*mean;
    const float inv  = 1.f/sqrtf(var+1e-5f);
    sc0[t] = bw0[t]*inv;
    sf0[t] = bb0[t] - mean*sc0[t];
  }
  __syncthreads();
  if (lane<32){
    const float v = yf[(size_t)n*120+lane]*sc0[lane] + sf0[lane];
    xvS[w][lane] = xf[(size_t)n*120+lane] + fmaxf(v,0.f);
  }
  __syncthreads();
  const float inv32 = 0.17677669529663688110f;
  if (lane<32){
    float g=0.f;
    #pragma unroll 8
    for(int k=0;k<32;++k) g += xvS[w][k]*w1[k*32+lane];
    h1S[w][lane] = fmaxf(g*inv32, 0.f);
  }
  __syncthreads();
  if (lane<16){
    float g=b2[lane];
    #pragma unroll 8
    for(int k=0;k<32;++k) g += h1S[w][k]*w2[k*16+lane];
    h2S[w][lane]=fmaxf(g,0.f);
  }
  __syncthreads();
  if (lane<2){
    float g=b3[lane];
    #pragma unroll
    for(int k=0;k<16;++k) g += h2S[w][k]*w3[k*2+lane];
    out[n*2+lane]=g;
  }
}

extern "C" void kernel_launch(void* const* d_in, const int* in_sizes, int n_in,
                              void* d_out, int out_size, void* d_ws, size_t ws_size,
                              hipStream_t stream) {
  const float* positions = (const float*)d_in[0];
  const float* W_emb  = (const float*)d_in[1];
  const float* tp_w   = (const float*)d_in[2];
  const float* lin_W0 = (const float*)d_in[3];
  const float* lin_W1 = (const float*)d_in[4];
  const float* lin_W2 = (const float*)d_in[5];
  const float* bn_w0  = (const float*)d_in[6];
  const float* bn_b0  = (const float*)d_in[7];
  const float* bn_w1  = (const float*)d_in[8];
  const float* bn_w2  = (const float*)d_in[9];
  const float* Wf1 = (const float*)d_in[10];
  const float* Wf2 = (const float*)d_in[11];
  const float* bf2 = (const float*)d_in[12];
  const float* Wf3 = (const float*)d_in[13];
  const float* bf3 = (const float*)d_in[14];

  if (ws_size < WS_FLOATS*sizeof(float)) return;

  float* ws    = (float*)d_ws;
  float* Kbuf  = ws + OFF_K;
  int*   cnt   = (int*)(ws + OFF_CNT);
  int*   rev   = (int*)(ws + OFF_REV);
  float* stats = ws + OFF_STATS;   // 3 layers x 8 slots x (32 pA | 96 pB), slot-major
  float* xf = ws + OFF_XF;
  float* yf = ws + OFF_YF;

  // SoA position arrays alias the head of yf (dead after k_knn8; first msg rewrites yf)
  float* xs = yf;
  float* ysA = yf + NN;
  float* zs = yf + 2*NN;
  float* qs = yf + 3*NN;

  // K tensor: pure constants — host-computed once, tiny async upload.
  if (!g_Kinit){ h_computeK(); g_Kinit = true; }
  hipMemcpyAsync(Kbuf, g_Khost, 405*sizeof(float), hipMemcpyHostToDevice, stream);

  k_setup<<<3916,256,0,stream>>>(positions, W_emb, xf, xs, ysA, zs, qs, cnt, stats);
  k_knn8<<<NN/8,256,0,stream>>>(xs, ysA, zs, qs, cnt, rev);

  if (g_coop != 0){
    float* outp = (float*)d_out;
    void* args[] = { (void*)&positions, (void*)&cnt, (void*)&rev, (void*)&Kbuf,
                     (void*)&xf, (void*)&tp_w, (void*)&lin_W0, (void*)&lin_W1, (void*)&lin_W2,
                     (void*)&stats, (void*)&yf, (void*)&bn_w0, (void*)&bn_b0,
                     (void*)&bn_w1, (void*)&bn_w2, (void*)&Wf1, (void*)&Wf2,
                     (void*)&bf2, (void*)&Wf3, (void*)&bf3, (void*)&outp };
    hipError_t e = hipLaunchCooperativeKernel((const void*)k_layers,
                     dim3(LGRID), dim3(256), args, 0, stream);
    if (e == hipSuccess){ g_coop = 1; return; }
    (void)hipGetLastError();   // clear sticky error, fall through to legacy
    g_coop = 0;
  }

  for(int l=0;l<3;++l){
    float* pA = stats + l*1024;      // [8][32]
    float* pB = pA + 256;            // [8][96]
    k_msg<<<NN/4,256,0,stream>>>(positions, cnt, rev, Kbuf, xf,
                              tp_w + l*144, lin_W0 + l*40*32, lin_W1 + l*40*16, lin_W2 + l*64*8,
                              pA, pB, yf);
    if (l<2){
      k_norm<<<(NN*120+255)/256,256,0,stream>>>(yf, pA, pB,
                              bn_w0 + l*32, bn_b0 + l*32, bn_w1 + l*16, bn_w2 + l*8,
                              xf);
    }
  }
  k_normmlp<<<NN/4,256,0,stream>>>(yf, xf, stats + 2*1024, stats + 2*1024 + 256,
                              bn_w0 + 64, bn_b0 + 64,
                              Wf1, Wf2, bf2, Wf3, bf3, (float*)d_out);
}

// Round 14
// 267.230 us; speedup vs baseline: 1.0317x; 1.0317x over previous
//
#include <hip/hip_runtime.h>
#include <math.h>

#define NN 8192
#define REV_CAP 48
#define KNN_CAP 384   // per-node survivor cap (E[survivors]~72; P(overflow) astronomically small)
#define PF 12         // k_msg edge-gather prefetch depth

// ---- ws layout (float element offsets) ----
static const size_t OFF_K     = 0;        // 405
static const size_t OFF_CNT   = 512;      // int[8192]
static const size_t OFF_REV   = 8704;     // int[8192*48]
static const size_t OFF_STATS = 401920;   // 3 layers x (8 slots x (32 pA | 96 pB)) = 3x1024, slot-major
static const size_t OFF_XF    = 406528;   // 8192*120 interleaved features
static const size_t OFF_YF    = 1389568;  // 8192*120 outputs (head aliased as SoA x/y/z/q for KNN)
static const size_t WS_FLOATS = 2372608;

// =================== K tensor math — HOST, once (pure constants) ===================
static double h_dfact(int n){ double r=1.0; for(int i=2;i<=n;++i) r*=(double)i; return r; }

static double h_dcg(int j1,int m1,int j2,int m2,int j3,int m3){
  if (m1+m2!=m3) return 0.0;
  if (j3 < abs(j1-j2) || j3 > j1+j2) return 0.0;
  double pre = sqrt((double)(2*j3+1)*h_dfact(j3+j1-j2)*h_dfact(j3-j1+j2)*h_dfact(j1+j2-j3)/h_dfact(j1+j2+j3+1));
  pre *= sqrt(h_dfact(j3+m3)*h_dfact(j3-m3)*h_dfact(j1-m1)*h_dfact(j1+m1)*h_dfact(j2-m2)*h_dfact(j2+m2));
  double s=0.0;
  for(int k=0;k<=j1+j2-j3;++k){
    int d1=j1+j2-j3-k, d2=j1-m1-k, d3=j2+m2-k, d4=j3-j2+m1+k, d5=j3-j1-m2+k;
    if(d1<0||d2<0||d3<0||d4<0||d5<0) continue;
    double den = h_dfact(k)*h_dfact(d1)*h_dfact(d2)*h_dfact(d3)*h_dfact(d4)*h_dfact(d5);
    s += ((k&1)? -1.0: 1.0)/den;
  }
  return pre*s;
}

static int h_qrow(int l,int r,int* col,double* re,double* im){
  const double s = 0.70710678118654752440;
  if (r==l){ col[0]=l; re[0]=1.0; im[0]=0.0; return 1; }
  if (r>l){ int m=r-l;
    col[0]=l+m; re[0]=((m&1)?-s:s); im[0]=0.0;
    col[1]=l-m; re[1]=s;            im[1]=0.0;
  } else { int m=l-r;
    col[0]=l+m; re[0]=0.0; im[0]=((m&1)? s : -s);
    col[1]=l-m; re[1]=0.0; im[1]=s;
  }
  return 2;
}

static float g_Khost[405];
static bool  g_Kinit = false;

static void h_computeK(){
  const int sizes[9]={1,25,9,45,75,25,25,75,125};
  const int l1s[9]={0,0,1,1,1,2,2,2,2};
  const int l2s[9]={0,2,0,2,2,0,2,2,2};
  const int l3s[9]={0,2,1,1,2,2,0,1,2};
  for(int tid=0; tid<405; ++tid){
    int p=0, rem=tid;
    for(p=0;p<9;++p){ if(rem < sizes[p]) break; rem -= sizes[p]; }
    const int l1=l1s[p], l2=l2s[p], l3=l3s[p];
    const int n1=2*l1+1, n2=2*l2+1;
    const int c = rem/(n1*n2); const int r2 = rem%(n1*n2); const int a=r2/n2; const int b=r2%n2;

    int c3[2],c1[2],c2[2]; double re3[2],im3[2],re1[2],im1[2],re2[2],im2[2];
    const int nc3 = h_qrow(l3,c,c3,re3,im3);
    const int nc1 = h_qrow(l1,a,c1,re1,im1);
    const int nc2 = h_qrow(l2,b,c2,re2,im2);

    double accRe=0, accIm=0;
    for(int i3=0;i3<nc3;++i3){
      const double q3re=re3[i3], q3im=-im3[i3];
      for(int i1=0;i1<nc1;++i1){
        const double pre_re = q3re*re1[i1] - q3im*im1[i1];
        const double pre_im = q3re*im1[i1] + q3im*re1[i1];
        for(int i2=0;i2<nc2;++i2){
          const double cgv = h_dcg(l1, c1[i1]-l1, l2, c2[i2]-l2, l3, c3[i3]-l3);
          if (cgv==0.0) continue;
          accRe += (pre_re*re2[i2] - pre_im*im2[i2])*cgv;
          accIm += (pre_re*im2[i2] + pre_im*re2[i2])*cgv;
        }
      }
    }
    const bool useImag = ((l1+l2+l3)&1)!=0;
    g_Khost[tid] = (float)(useImag? accIm : accRe);
  }
}

// =================== fused setup: xf init | SoA+q | cnt | stats-zero ===================
__global__ __launch_bounds__(256) void k_setup(const float* __restrict__ pos,
        const float* __restrict__ W_emb,
        float* __restrict__ xf,
        float* __restrict__ xs, float* __restrict__ ys, float* __restrict__ zs,
        float* __restrict__ qs,
        int* __restrict__ cnt, float* __restrict__ stats){
  int idx = blockIdx.x*256 + threadIdx.x;
  if (idx < 983040) { const int c = idx%120; xf[idx] = (c<32)? W_emb[c] : 0.f; return; }
  idx -= 983040;
  if (idx < 8192) {
    const float x=pos[3*idx], y=pos[3*idx+1], z=pos[3*idx+2];
    xs[idx]=x; ys[idx]=y; zs[idx]=z; qs[idx]=0.5f*(x*x+y*y+z*z);
    return;
  }
  idx -= 8192;
  if (idx < 8192) { cnt[idx]=0; return; }
  idx -= 8192;
  if (idx < 3072) stats[idx]=0.f;   // 3 layers x 8 slots x (32 pA | 96 pB)
}

// sortable key: monotonic float->uint map (neg floats < pos floats, order preserved)
__device__ __forceinline__ unsigned fkey(float f){
  const unsigned b = __float_as_uint(f);
  return (b & 0x80000000u) ? ~b : (b | 0x80000000u);
}

// exact 9th-smallest of the 128-element per-wave (m1,m2) multiset via ballot radix-select
__device__ __forceinline__ float rsel9_T(float m1, float m2){
  const unsigned kk1 = fkey(m1), kk2 = fkey(m2);
  unsigned P = 0u; int need = 9;
  #pragma unroll 1
  for(int bit=31; bit>=0; --bit){
    const unsigned pref = P >> bit;
    const int c0 = __popcll(__ballot((kk1>>bit)==pref)) + __popcll(__ballot((kk2>>bit)==pref));
    if (need > c0){ need -= c0; P |= (1u<<bit); }
  }
  return __uint_as_float((P & 0x80000000u) ? (P & 0x7fffffffu) : ~P);
}

// radix-select the exact 9th-smallest (key,id)-lex threshold over KMAX regs/lane,
// then push the selected SET (order irrelevant: 9 distinct targets).
#define RSELECT_PUSH(KMAX) do{ \
  unsigned P = 0u; int need = 9; \
  _Pragma("unroll 1") \
  for(int bit=31; bit>=0; --bit){ \
    const unsigned pref = P >> bit; \
    int c0 = 0; \
    _Pragma("unroll") \
    for(int k=0;k<KMAX;++k) c0 += __popcll(__ballot((ku[k]>>bit)==pref)); \
    if (need > c0){ need -= c0; P |= (1u<<bit); } \
  } \
  int c_eq = 0; \
  _Pragma("unroll") \
  for(int k=0;k<KMAX;++k) c_eq += __popcll(__ballot(ku[k]==P)); \
  bool tsel[KMAX]; \
  _Pragma("unroll") \
  for(int k=0;k<KMAX;++k) tsel[k] = (ku[k]==P); \
  if (c_eq > need){ \
    _Pragma("unroll") \
    for(int k=0;k<KMAX;++k) tsel[k]=false; \
    for(int r=0;r<need;++r){ \
      int mid = 0x7fffffff; \
      _Pragma("unroll") \
      for(int k=0;k<KMAX;++k) if (ku[k]==P && !tsel[k] && il[k]<mid) mid = il[k]; \
      _Pragma("unroll") \
      for(int s=32;s>0;s>>=1){ const int om = __shfl_xor(mid,s,64); mid = (om<mid)? om : mid; } \
      _Pragma("unroll") \
      for(int k=0;k<KMAX;++k) if (ku[k]==P && il[k]==mid) tsel[k]=true; \
    } \
  } \
  _Pragma("unroll") \
  for(int k=0;k<KMAX;++k){ \
    const bool take = (ku[k] < P) || tsel[k]; \
    const int ix = il[k]; \
    if (take && ix != node){ \
      int cpos = atomicAdd(&cnt[ix],1); \
      if (cpos < REV_CAP) rev[ix*REV_CAP + cpos] = node; \
    } \
  } \
}while(0)

// =================== exact 9-NN: 2 nodes/wave, 1-deep prefetch (r11-proven BEST form) ===================
// Variant history (all refcheck'd): 1-node/wave 48.5us; 2-node/1-deep 44.5us (BEST);
// 2-node/2-deep 47us (hand pipelining lost to compiler scheduling); 4-node r1 and
// LDS-staging r2/r6 worse. Latency-bound at 37% VALU / 13.5 TB/s; grid-capped occupancy.
__global__ __launch_bounds__(256, 8) void k_knn8(const float* __restrict__ xs,
                                              const float* __restrict__ ys,
                                              const float* __restrict__ zs,
                                              const float* __restrict__ qs,
                                              int* __restrict__ cnt, int* __restrict__ rev){
  const int lane = threadIdx.x & 63;
  const int w    = threadIdx.x >> 6;
  const int n0   = blockIdx.x*8 + w*2;      // this wave's nodes: n0, n0+1
  const int w2   = w*2;
  __shared__ float sdist[8][KNN_CAP];
  __shared__ int   sidx[8][KNN_CAP];
  __shared__ int   scount[8];
  if (threadIdx.x < 8) scount[threadIdx.x]=0;
  __syncthreads();

  const float px0 = xs[n0],   py0 = ys[n0],   pz0 = zs[n0];
  const float px1 = xs[n0+1], py1 = ys[n0+1], pz1 = zs[n0+1];

  // Phase 1: per-lane top-2 per node over first 1024 candidates, branchless
  float m1a=INFINITY, m2a=INFINITY, m1b=INFINITY, m2b=INFINITY;
  for(int c=0;c<4;++c){
    const int base = (c*64 + lane)*4;
    const float4 fx = *(const float4*)(xs + base);
    const float4 fy = *(const float4*)(ys + base);
    const float4 fz = *(const float4*)(zs + base);
    const float4 fq = *(const float4*)(qs + base);
    const float cx[4]={fx.x,fx.y,fx.z,fx.w};
    const float cy[4]={fy.x,fy.y,fy.z,fy.w};
    const float cz[4]={fz.x,fz.y,fz.z,fz.w};
    const float cq[4]={fq.x,fq.y,fq.z,fq.w};
    #pragma unroll
    for(int q=0;q<4;++q){
      const float s0 = fmaf(-px0,cx[q], fmaf(-py0,cy[q], fmaf(-pz0,cz[q], cq[q])));
      const float s1 = fmaf(-px1,cx[q], fmaf(-py1,cy[q], fmaf(-pz1,cz[q], cq[q])));
      float hi;
      hi = fmaxf(m1a, s0); m1a = fminf(m1a, s0); m2a = fminf(m2a, hi);
      hi = fmaxf(m1b, s1); m1b = fminf(m1b, s1); m2b = fminf(m2b, hi);
    }
  }
  const float T0 = rsel9_T(m1a, m2a);
  const float T1 = rsel9_T(m1b, m2b);

  // Phase 2: filter all 8192 candidates for both nodes, 1-deep load prefetch
  {
    const int b0 = lane*4;
    float4 nfx = *(const float4*)(xs + b0);
    float4 nfy = *(const float4*)(ys + b0);
    float4 nfz = *(const float4*)(zs + b0);
    float4 nfq = *(const float4*)(qs + b0);
    for(int c=0;c<32;++c){
      const float4 fx=nfx, fy=nfy, fz=nfz, fq=nfq;
      const int cbase = (c*64 + lane)*4;
      if (c<31){
        const int nb2 = ((c+1)*64 + lane)*4;
        nfx = *(const float4*)(xs + nb2);
        nfy = *(const float4*)(ys + nb2);
        nfz = *(const float4*)(zs + nb2);
        nfq = *(const float4*)(qs + nb2);
      }
      const float cx[4]={fx.x,fx.y,fx.z,fx.w};
      const float cy[4]={fy.x,fy.y,fy.z,fy.w};
      const float cz[4]={fz.x,fz.y,fz.z,fz.w};
      const float cq[4]={fq.x,fq.y,fq.z,fq.w};
      #pragma unroll
      for(int q=0;q<4;++q){
        const float s0 = fmaf(-px0,cx[q], fmaf(-py0,cy[q], fmaf(-pz0,cz[q], cq[q])));
        const float s1 = fmaf(-px1,cx[q], fmaf(-py1,cy[q], fmaf(-pz1,cz[q], cq[q])));
        if (s0 <= T0){
          int pos = atomicAdd(&scount[w2],1);
          if (pos < KNN_CAP){ sdist[w2][pos]=s0; sidx[w2][pos]=cbase+q; }
        }
        if (s1 <= T1){
          int pos = atomicAdd(&scount[w2+1],1);
          if (pos < KNN_CAP){ sdist[w2+1][pos]=s1; sidx[w2+1][pos]=cbase+q; }
        }
      }
    }
  }
  __syncthreads();

  // Phase 3: exact top-9 per node, (key,id)-lexicographic, radix-select + set push
  #pragma unroll 1
  for(int u=0;u<2;++u){
    const int node = n0+u;
    const int s_   = w2+u;
    int m = scount[s_]; if (m > KNN_CAP) m = KNN_CAP;
    unsigned ku[KNN_CAP/64]; int il[KNN_CAP/64];
    #pragma unroll
    for(int k=0;k<KNN_CAP/64;++k){
      const int j = lane + 64*k;
      if (j < m){ ku[k]=fkey(sdist[s_][j]); il[k]=sidx[s_][j]; }
      else      { ku[k]=0xffffffffu;        il[k]=0x7fffffff; }
    }
    if (m <= 128) RSELECT_PUSH(2);    // common case (E[m]~72): 2-reg ballots
    else          RSELECT_PUSH(6);    // exact fallback
  }
}

// =================== moment-based message passing + fused stats partials (r8/r11-proven form) ===================
// r9 lesson: staging W0/W1/W2 in LDS dropped occupancy 6->4 blocks/CU (+15us) — occupancy-
// sensitive; weights are L2-resident, read from global. r13 lesson: cooperative grid.sync
// on 8-XCD costs ~150us/barrier (cross-XCD atomic spin) — launch boundaries are cheaper.
// stats layout per layer (slot-major, XCD-local): pA[slot*32+ch], pB[slot*96+ch], slot=blockIdx&7
// (r4 lesson: channel-major put all 8 slots in one cache line -> cross-XCD ping-pong, +8MB HBM).
__global__ __launch_bounds__(256) void k_msg(
  const float* __restrict__ pos,
  const int* __restrict__ cnt, const int* __restrict__ rev,
  const float* __restrict__ Kbuf,
  const float* __restrict__ xf,
  const float* __restrict__ tpw,
  const float* __restrict__ W0, const float* __restrict__ W1, const float* __restrict__ W2,
  float* __restrict__ pA, float* __restrict__ pB,
  float* __restrict__ yf)
{
  const int t = threadIdx.x;
  const int w = t >> 6;
  const int lane = t & 63;
  const int n = blockIdx.x*4 + w;

  __shared__ float KL[405];
  __shared__ float TW[144];
  __shared__ float momPS[4][720];   // [0,120): momP ; [120,720): momS flattened (c*5+j)
  __shared__ float aS[4][480];
  __shared__ int   eIdx[4][REV_CAP];
  __shared__ float eSh[4][5][REV_CAP];
  __shared__ float bA[32], bB[96];
  for(int q=t;q<405;q+=256) KL[q]=Kbuf[q];
  for(int q=t;q<144;q+=256) TW[q]=tpw[q];
  if (t<96){ bB[t]=0.f; if(t<32) bA[t]=0.f; }

  // Stage 1a: parallel edge geometry (lane e < deg owns edge e)
  const int deg0 = cnt[n];
  const int deg = (deg0<REV_CAP)? deg0 : REV_CAP;
  const float pnx=pos[3*n], pny=pos[3*n+1], pnz=pos[3*n+2];
  const float s15 = 3.8729833462f, s5c = 2.2360679775f;
  if (lane < deg){
    const int i = rev[n*REV_CAP+lane];
    eIdx[w][lane] = i;
    const float ex = pnx - pos[3*i], ey = pny - pos[3*i+1], ez = pnz - pos[3*i+2];
    const float rn = sqrtf(ex*ex+ey*ey+ez*ez) + 1e-12f;
    const float ux=ex/rn, uy=ey/rn, uz=ez/rn;
    eSh[w][0][lane]=s15*ux*uy;
    eSh[w][1][lane]=s15*uy*uz;
    eSh[w][2][lane]=0.5f*s5c*(3.f*uz*uz-1.f);
    eSh[w][3][lane]=s15*ux*uz;
    eSh[w][4][lane]=0.5f*s15*(ux*ux-uy*uy);
  }
  __syncthreads();

  // Stage 1b: moment accumulation with prefetched gathers
  const int c0 = lane*2;
  float mp0=0.f, mp1=0.f;
  float ms0[5], ms1[5];
  #pragma unroll
  for(int j=0;j<5;++j){ ms0[j]=0.f; ms1[j]=0.f; }

  int idxr[PF];
  #pragma unroll
  for(int k=0;k<PF;++k) idxr[k] = (k<deg)? eIdx[w][k] : 0;
  float2 fr[PF];
  if (lane<60){
    #pragma unroll
    for(int k=0;k<PF;++k) fr[k] = *(const float2*)(xf + (size_t)idxr[k]*120 + c0);
  }
  #pragma unroll
  for(int k=0;k<PF;++k){
    if (k<deg){
      const float sh0=eSh[w][0][k], sh1=eSh[w][1][k], sh2=eSh[w][2][k];
      const float sh3=eSh[w][3][k], sh4=eSh[w][4][k];
      if (lane<60){
        const float2 f = fr[k];
        mp0 += f.x; mp1 += f.y;
        ms0[0]+=f.x*sh0; ms0[1]+=f.x*sh1; ms0[2]+=f.x*sh2; ms0[3]+=f.x*sh3; ms0[4]+=f.x*sh4;
        ms1[0]+=f.y*sh0; ms1[1]+=f.y*sh1; ms1[2]+=f.y*sh2; ms1[3]+=f.y*sh3; ms1[4]+=f.y*sh4;
      }
    }
  }
  for(int e=PF;e<deg;++e){   // rare tail (deg>PF)
    const int i = eIdx[w][e];
    const float sh0=eSh[w][0][e], sh1=eSh[w][1][e], sh2=eSh[w][2][e];
    const float sh3=eSh[w][3][e], sh4=eSh[w][4][e];
    if (lane<60){
      const float2 f = *(const float2*)(xf + (size_t)i*120 + c0);
      mp0 += f.x; mp1 += f.y;
      ms0[0]+=f.x*sh0; ms0[1]+=f.x*sh1; ms0[2]+=f.x*sh2; ms0[3]+=f.x*sh3; ms0[4]+=f.x*sh4;
      ms1[0]+=f.y*sh0; ms1[1]+=f.y*sh1; ms1[2]+=f.y*sh2; ms1[3]+=f.y*sh3; ms1[4]+=f.y*sh4;
    }
  }
  if (lane<60){
    momPS[w][c0]=mp0; momPS[w][c0+1]=mp1;
    #pragma unroll
    for(int j=0;j<5;++j){ momPS[w][120+c0*5+j]=ms0[j]; momPS[w][120+(c0+1)*5+j]=ms1[j]; }
  }
  __syncthreads();

  // Stage 2: balanced K-contraction interpreter — 480 dots/node over 64 lanes.
  #pragma unroll 1
  for(int e=lane; e<480; e+=64){
    int a, b, L, dst; float rw;
    if (e<32){        const int u=e;                            a=0;        b=u;                  L=1;  rw=TW[u];     dst=u; }
    else if (e<192){  const int i=e-32,  u=i/5, o=i%5;          a=1+o*5;    b=120+u*5;            L=5;  rw=TW[32+u];  dst=160+u*5+o; }
    else if (e<240){  const int i=e-192, u=i/3, o=i%3;          a=26+o*3;   b=32+u*3;             L=3;  rw=TW[64+u];  dst=40+u*3+o; }
    else if (e<288){  const int i=e-240, u=i/3, o=i%3;          a=35+o*15;  b=120+(32+u*3)*5;     L=15; rw=TW[80+u];  dst=40+(16+u)*3+o; }
    else if (e<368){  const int i=e-288, u=i/5, o=i%5;          a=80+o*15;  b=120+(32+u*3)*5;     L=15; rw=TW[96+u];  dst=160+(32+u)*5+o; }
    else if (e<408){  const int i=e-368, u=i/5, o=i%5;          a=155+o*5;  b=80+u*5;             L=5;  rw=TW[112+u]; dst=160+(48+u)*5+o; }
    else if (e<416){  const int u=e-408;                        a=180;      b=120+(80+u*5)*5;     L=25; rw=TW[120+u]; dst=32+u; }
    else if (e<440){  const int i=e-416, u=i/3, o=i%3;          a=205+o*25; b=120+(80+u*5)*5;     L=25; rw=TW[128+u]; dst=40+(32+u)*3+o; }
    else {            const int i=e-440, u=i/5, o=i%5;          a=280+o*25; b=120+(80+u*5)*5;     L=25; rw=TW[136+u]; dst=160+(56+u)*5+o; }
    float g=0.f;
    #pragma unroll 1
    for(int k=0;k<L;++k) g += KL[a+k]*momPS[w][b+k];
    aS[w][dst] = rw*g;
  }
  __syncthreads();

  // Stage 3: linear mixes, write yf[n][120], accumulate block stats partials in LDS
  const float inv40 = 0.15811388300841896660f;
  for(int q=lane;q<120;q+=64){
    float out; int chan;
    if (q<32){
      float g=0.f;
      for(int uu=0;uu<40;++uu) g += aS[w][uu]*W0[uu*32+q];
      out = g*inv40; chan = q;
    } else if (q<80){
      const int e=q-32, v=e/3, m=e%3;
      float g=0.f;
      for(int uu=0;uu<40;++uu) g += aS[w][40+uu*3+m]*W1[uu*16+v];
      out = g*inv40; chan = 32+v;
    } else {
      const int e=q-80, tt=e/5, m=e%5;
      float g=0.f;
      for(int uu=0;uu<64;++uu) g += aS[w][160+uu*5+m]*W2[uu*8+tt];
      out = g*0.125f; chan = 48+tt;
    }
    yf[(size_t)n*120+q] = out;
    atomicAdd(&bB[chan], out*out);
    if (q<32) atomicAdd(&bA[q], out);
  }
  __syncthreads();
  // flush block partials to this XCD's exclusive slot lines
  if (t<96){
    const int slot = blockIdx.x & 7;
    atomicAdd(&pB[slot*96 + t], bB[t]);
    if (t<32) atomicAdd(&pA[slot*32 + t], bA[t]);
  }
}

// =================== normalize + relu + residual (layers 0,1): per-block finalize + apply ===================
__global__ __launch_bounds__(256) void k_norm(const float* __restrict__ yf,
                       const float* __restrict__ pA, const float* __restrict__ pB,
                       const float* __restrict__ bw0,const float* __restrict__ bb0,
                       const float* __restrict__ bw1,const float* __restrict__ bw2,
                       float* __restrict__ xf){
  __shared__ float sc[96], sf[32];
  const int t = threadIdx.x;
  if (t<96){
    float sB=0.f;
    #pragma unroll
    for(int k=0;k<8;++k) sB += pB[k*96+t];
    float scale;
    if (t<32){
      float sA=0.f;
      #pragma unroll
      for(int k=0;k<8;++k) sA += pA[k*32+t];
      const float mean = sA*(1.f/8192.f);
      const float var  = sB*(1.f/8192.f) - mean*mean;
      const float inv  = 1.f/sqrtf(var+1e-5f);
      scale = bw0[t]*inv;
      sf[t] = bb0[t] - mean*scale;
    } else if (t<48){
      scale = bw1[t-32]/sqrtf(sB*(1.f/(8192.f*3.f))+1e-5f);
    } else {
      scale = bw2[t-48]/sqrtf(sB*(1.f/(8192.f*5.f))+1e-5f);
    }
    sc[t]=scale;
  }
  __syncthreads();
  const int idx = blockIdx.x*256 + t;
  if (idx >= NN*120) return;
  const int c = idx%120;
  const int chan = (c<32)? c : ((c<80)? 32+(c-32)/3 : 48+(c-80)/5);
  const float v = yf[idx]*sc[chan] + ((c<32)? sf[c] : 0.f);
  xf[idx] += fmaxf(v,0.f);
}

// =================== fused layer-3 norm (x0 only) + final MLP: wave-per-node ===================
__global__ __launch_bounds__(256) void k_normmlp(const float* __restrict__ yf,
                                             const float* __restrict__ xf,
                                             const float* __restrict__ pA, const float* __restrict__ pB,
                                             const float* __restrict__ bw0,const float* __restrict__ bb0,
                                             const float* __restrict__ Wf1,const float* __restrict__ Wf2,
                                             const float* __restrict__ bf2,const float* __restrict__ Wf3,
                                             const float* __restrict__ bf3, float* __restrict__ out){
  __shared__ float w1[1024], w2[512], w3[32], b2[16], b3[2], sc0[32], sf0[32];
  __shared__ float xvS[4][32], h1S[4][32], h2S[4][16];
  const int t=threadIdx.x;
  const int w = t>>6, lane = t&63;
  const int n = blockIdx.x*4 + w;
  for(int q=t;q<1024;q+=256) w1[q]=Wf1[q];
  for(int q=t;q<512;q+=256)  w2[q]=Wf2[q];
  if(t<32) w3[t]=Wf3[t];
  if(t<16) b2[t]=bf2[t];
  if(t<2)  b3[t]=bf3[t];
  if(t<32){
    float sA=0.f, sB=0.f;
    #pragma unroll
    for(int k=0;k<8;++k){ sA += pA[k*32+t]; sB += pB[k*96+t]; }
    const float mean = sA*(1.f/8192.f);
    const float var  = sB*(1.f/8192.f) - mean*mean;
    const float inv  = 1.f/sqrtf(var+1e-5f);
    sc0[t] = bw0[t]*inv;
    sf0[t] = bb0[t] - mean*sc0[t];
  }
  __syncthreads();
  if (lane<32){
    const float v = yf[(size_t)n*120+lane]*sc0[lane] + sf0[lane];
    xvS[w][lane] = xf[(size_t)n*120+lane] + fmaxf(v,0.f);
  }
  __syncthreads();
  const float inv32 = 0.17677669529663688110f;
  if (lane<32){
    float g=0.f;
    #pragma unroll 8
    for(int k=0;k<32;++k) g += xvS[w][k]*w1[k*32+lane];
    h1S[w][lane] = fmaxf(g*inv32, 0.f);
  }
  __syncthreads();
  if (lane<16){
    float g=b2[lane];
    #pragma unroll 8
    for(int k=0;k<32;++k) g += h1S[w][k]*w2[k*16+lane];
    h2S[w][lane]=fmaxf(g,0.f);
  }
  __syncthreads();
  if (lane<2){
    float g=b3[lane];
    #pragma unroll
    for(int k=0;k<16;++k) g += h2S[w][k]*w3[k*2+lane];
    out[n*2+lane]=g;
  }
}

extern "C" void kernel_launch(void* const* d_in, const int* in_sizes, int n_in,
                              void* d_out, int out_size, void* d_ws, size_t ws_size,
                              hipStream_t stream) {
  const float* positions = (const float*)d_in[0];
  const float* W_emb  = (const float*)d_in[1];
  const float* tp_w   = (const float*)d_in[2];
  const float* lin_W0 = (const float*)d_in[3];
  const float* lin_W1 = (const float*)d_in[4];
  const float* lin_W2 = (const float*)d_in[5];
  const float* bn_w0  = (const float*)d_in[6];
  const float* bn_b0  = (const float*)d_in[7];
  const float* bn_w1  = (const float*)d_in[8];
  const float* bn_w2  = (const float*)d_in[9];
  const float* Wf1 = (const float*)d_in[10];
  const float* Wf2 = (const float*)d_in[11];
  const float* bf2 = (const float*)d_in[12];
  const float* Wf3 = (const float*)d_in[13];
  const float* bf3 = (const float*)d_in[14];

  if (ws_size < WS_FLOATS*sizeof(float)) return;

  float* ws    = (float*)d_ws;
  float* Kbuf  = ws + OFF_K;
  int*   cnt   = (int*)(ws + OFF_CNT);
  int*   rev   = (int*)(ws + OFF_REV);
  float* stats = ws + OFF_STATS;   // 3 layers x 8 slots x (32 pA | 96 pB), slot-major
  float* xf = ws + OFF_XF;
  float* yf = ws + OFF_YF;

  // SoA position arrays alias the head of yf (dead after k_knn8; first k_msg rewrites yf)
  float* xs = yf;
  float* ysA = yf + NN;
  float* zs = yf + 2*NN;
  float* qs = yf + 3*NN;

  // K tensor: pure constants — host-computed once, tiny async upload.
  if (!g_Kinit){ h_computeK(); g_Kinit = true; }
  hipMemcpyAsync(Kbuf, g_Khost, 405*sizeof(float), hipMemcpyHostToDevice, stream);

  k_setup<<<3916,256,0,stream>>>(positions, W_emb, xf, xs, ysA, zs, qs, cnt, stats);
  k_knn8<<<NN/8,256,0,stream>>>(xs, ysA, zs, qs, cnt, rev);

  for(int l=0;l<3;++l){
    float* pA = stats + l*1024;      // [8][32]
    float* pB = pA + 256;            // [8][96]
    k_msg<<<NN/4,256,0,stream>>>(positions, cnt, rev, Kbuf, xf,
                              tp_w + l*144, lin_W0 + l*40*32, lin_W1 + l*40*16, lin_W2 + l*64*8,
                              pA, pB, yf);
    if (l<2){
      k_norm<<<(NN*120+255)/256,256,0,stream>>>(yf, pA, pB,
                              bn_w0 + l*32, bn_b0 + l*32, bn_w1 + l*16, bn_w2 + l*8,
                              xf);
    }
  }
  k_normmlp<<<NN/4,256,0,stream>>>(yf, xf, stats + 2*1024, stats + 2*1024 + 256,
                              bn_w0 + 64, bn_b0 + 64,
                              Wf1, Wf2, bf2, Wf3, bf3, (float*)d_out);
}